// Round 1
// baseline (12093.958 us; speedup 1.0000x reference)
//
#include <hip/hip_runtime.h>

// ---------------------------------------------------------------------------
// DiGCN_IB_3MixBN_SymCat: full-graph DiGCN with inception blocks.
// N=50000 nodes, E=800000 edges per set (5 sets), dims 128/128/64, f32.
//
// Structure per call:
//   1. degree + rsqrt + per-edge norm arrays for the 4 dgcn-normalized sets
//   2. transpose torch-layout weights into ws ([K][M] for GEMM)
//   3. 9 LDS-tiled f32 GEMMs
//   4. 10 atomic scatter-adds (hardware global_atomic_add_f32)
// ---------------------------------------------------------------------------

static inline int cdiv(int a, int b) { return (a + b - 1) / b; }

__global__ void k_deg(const int* __restrict__ src, const float* __restrict__ w,
                      float* __restrict__ deg, int E) {
  int e = blockIdx.x * blockDim.x + threadIdx.x;
  if (e < E) unsafeAtomicAdd(&deg[src[e]], w ? w[e] : 1.0f);
}

__global__ void k_rsqrt(float* __restrict__ d, int n) {
  int i = blockIdx.x * blockDim.x + threadIdx.x;
  if (i < n) {
    float v = d[i];
    d[i] = (v > 0.0f) ? rsqrtf(v) : 0.0f;
  }
}

__global__ void k_norm(const int* __restrict__ src, const int* __restrict__ dst,
                       const float* __restrict__ w, const float* __restrict__ dinv,
                       float* __restrict__ nrm, int E) {
  int e = blockIdx.x * blockDim.x + threadIdx.x;
  if (e < E) {
    float ww = w ? w[e] : 1.0f;
    nrm[e] = dinv[src[e]] * ww * dinv[dst[e]];
  }
}

// src [R][C] row-major -> dst [C][R] row-major
__global__ void k_transpose(const float* __restrict__ s, float* __restrict__ d,
                            int R, int C) {
  int i = blockIdx.x * blockDim.x + threadIdx.x;
  if (i < R * C) {
    int r = i / C, c = i % C;
    d[(size_t)c * R + r] = s[i];
  }
}

__global__ void k_bias3(const float* __restrict__ a, const float* __restrict__ b,
                        const float* __restrict__ c, float* __restrict__ o, int n) {
  int i = blockIdx.x * blockDim.x + threadIdx.x;
  if (i < n) o[i] = a[i] + b[i] + c[i];
}

// OUT[dst[e]] += X[src[e]] * w[e]   (M floats per row)
template <int M>
__global__ __launch_bounds__(256) void k_scatter(
    const float* __restrict__ X, const int* __restrict__ src,
    const int* __restrict__ dst, const float* __restrict__ w,
    float* __restrict__ OUT, int E) {
  constexpr int TPE = M / 4;       // threads per edge (float4 each)
  constexpr int EPB = 256 / TPE;   // edges per block
  int g = threadIdx.x / TPE;
  int l = threadIdx.x % TPE;
  int e = blockIdx.x * EPB + g;
  if (e >= E) return;
  int s = src[e], d = dst[e];
  float ww = w[e];
  float4 v = *reinterpret_cast<const float4*>(X + (size_t)s * M + l * 4);
  float* o = OUT + (size_t)d * M + l * 4;
  unsafeAtomicAdd(o + 0, v.x * ww);
  unsafeAtomicAdd(o + 1, v.y * ww);
  unsafeAtomicAdd(o + 2, v.z * ww);
  unsafeAtomicAdd(o + 3, v.w * ww);
}

// C[n][m] = act( sum_k A[n][k] * Wt[k][m] + bias[m] )
// A is split: k < K1 from A1 (row stride K1), k >= K1 from A2 (row stride K-K1).
// Tile: 64 nodes x M cols per block; 256 threads; 4 nodes x (M/16) cols/thread.
template <int K, int K1, int M, bool RELU_A, bool RELU_OUT>
__global__ __launch_bounds__(256) void k_gemm(
    const float* __restrict__ A1, const float* __restrict__ A2,
    const float* __restrict__ Wt, const float* __restrict__ bias,
    float* __restrict__ C, int N) {
  __shared__ float lds_a[64][65];   // +1 pad: distinct banks per node row
  __shared__ float lds_w[64][M];
  constexpr int JM = M / 16;
  float acc[4][JM];
#pragma unroll
  for (int i = 0; i < 4; i++)
#pragma unroll
    for (int j = 0; j < JM; j++) acc[i][j] = 0.0f;

  const int tid = threadIdx.x;
  const int mg = tid & 15;    // col group: m = mg + 16*j  (conflict-free lds_w)
  const int ng = tid >> 4;    // node group: node = ng*4 + i
  const int node_base = blockIdx.x * 64;
  const int lk = tid & 63;
  const int ln0 = tid >> 6;

  for (int k0 = 0; k0 < K; k0 += 64) {
    const float* A;
    int lda, kk0;
    if (k0 < K1) { A = A1; lda = K1; kk0 = k0; }
    else         { A = A2; lda = K - K1; kk0 = k0 - K1; }
#pragma unroll
    for (int i = 0; i < 16; i++) {
      int ln = i * 4 + ln0;
      int node = node_base + ln;
      float v = 0.0f;
      if (node < N) v = A[(size_t)node * lda + kk0 + lk];
      if (RELU_A) v = fmaxf(v, 0.0f);
      lds_a[ln][lk] = v;
    }
    for (int idx = tid; idx < 64 * M; idx += 256)
      lds_w[idx / M][idx % M] = Wt[(size_t)(k0 + idx / M) * M + (idx % M)];
    __syncthreads();
#pragma unroll 4
    for (int kk = 0; kk < 64; kk++) {
      float a[4];
#pragma unroll
      for (int i = 0; i < 4; i++) a[i] = lds_a[ng * 4 + i][kk];
#pragma unroll
      for (int j = 0; j < JM; j++) {
        float wv = lds_w[kk][mg + 16 * j];
#pragma unroll
        for (int i = 0; i < 4; i++) acc[i][j] = fmaf(a[i], wv, acc[i][j]);
      }
    }
    __syncthreads();
  }
#pragma unroll
  for (int i = 0; i < 4; i++) {
    int node = node_base + ng * 4 + i;
    if (node >= N) continue;
#pragma unroll
    for (int j = 0; j < JM; j++) {
      float v = acc[i][j];
      int m = mg + 16 * j;
      if (bias) v += bias[m];
      if (RELU_OUT) v = fmaxf(v, 0.0f);
      C[(size_t)node * M + m] = v;
    }
  }
}

extern "C" void kernel_launch(void* const* d_in, const int* in_sizes, int n_in,
                              void* d_out, int out_size, void* d_ws, size_t ws_size,
                              hipStream_t stream) {
  const float* x        = (const float*)d_in[0];
  const int*   ei_sym   = (const int*)d_in[1];
  const int*   ei_in    = (const int*)d_in[2];
  const float* in_w     = (const float*)d_in[3];
  const int*   ei_out   = (const int*)d_in[4];
  const float* out_w    = (const float*)d_in[5];
  const int*   ei_ib    = (const int*)d_in[6];
  const float* w_ib     = (const float*)d_in[7];
  const int*   ei_ib2   = (const int*)d_in[8];
  const float* w_ib2    = (const float*)d_in[9];
  const float* lin1_w   = (const float*)d_in[10];
  const float* lin2_w   = (const float*)d_in[11];
  const float* ib1_ln_w = (const float*)d_in[12];
  const float* ib1_ln_b = (const float*)d_in[13];
  const float* ib1_c1_w = (const float*)d_in[14];
  const float* ib1_c1_b = (const float*)d_in[15];
  const float* ib1_c2_w = (const float*)d_in[16];
  const float* ib1_c2_b = (const float*)d_in[17];
  const float* ib2_ln_w = (const float*)d_in[18];
  const float* ib2_ln_b = (const float*)d_in[19];
  const float* ib2_c1_w = (const float*)d_in[20];
  const float* ib2_c1_b = (const float*)d_in[21];
  const float* ib2_c2_w = (const float*)d_in[22];
  const float* ib2_c2_b = (const float*)d_in[23];
  const float* conv1_w  = (const float*)d_in[24];
  const float* conv1_b  = (const float*)d_in[25];

  const int N = in_sizes[0] / 128;
  const int E = in_sizes[1] / 2;

  // ---- workspace layout (f32 elements, 256B aligned blocks) ----
  float* ws = (float*)d_ws;
  size_t off = 0;
  auto alloc = [&](size_t n) {
    float* p = ws + off;
    off += (n + 63) & ~size_t(63);
    return p;
  };
  float* B0 = alloc((size_t)N * 128);  // symx_lin -> h
  float* B1 = alloc((size_t)N * 128);  // symx_agg -> symx2
  float* B2 = alloc((size_t)N * 128);  // hbase accumulators
  float* B3 = alloc((size_t)N * 128);  // xw scratch
  float* norm_sym = alloc(E);
  float* norm_in  = alloc(E);
  float* norm_out = alloc(E);
  float* norm_ib  = alloc(E);
  float* deg = alloc(4 * (size_t)N);   // [sym, in, out, ib]
  float* Wt_lin1  = alloc(128 * 128);
  float* Wt_ib1ln = alloc(128 * 128);
  float* Wt_ib2ln = alloc(128 * 128);
  float* Wt_conv1 = alloc(256 * 128);
  float* Wt_lin2  = alloc(128 * 64);
  float* bias1 = alloc(128);
  float* bias2 = alloc(128);

  const int TB = 256;
  const int gE = cdiv(E, TB);
  const int gG = cdiv(N, 64);        // GEMM node-tile grid
  const int gS128 = cdiv(E, 8);      // scatter<128>: 8 edges/block
  const int gS64  = cdiv(E, 16);     // scatter<64>: 16 edges/block

  // ---- 1. degrees -> dinv -> norms ----
  hipMemsetAsync(deg, 0, 4 * (size_t)N * sizeof(float), stream);
  k_deg<<<gE, TB, 0, stream>>>(ei_sym, nullptr, deg + 0 * N, E);
  k_deg<<<gE, TB, 0, stream>>>(ei_in,  in_w,    deg + 1 * N, E);
  k_deg<<<gE, TB, 0, stream>>>(ei_out, out_w,   deg + 2 * N, E);
  k_deg<<<gE, TB, 0, stream>>>(ei_ib,  nullptr, deg + 3 * N, E);
  k_rsqrt<<<cdiv(4 * N, TB), TB, 0, stream>>>(deg, 4 * N);
  k_norm<<<gE, TB, 0, stream>>>(ei_sym, ei_sym + E, nullptr, deg + 0 * N, norm_sym, E);
  k_norm<<<gE, TB, 0, stream>>>(ei_in,  ei_in + E,  in_w,    deg + 1 * N, norm_in,  E);
  k_norm<<<gE, TB, 0, stream>>>(ei_out, ei_out + E, out_w,   deg + 2 * N, norm_out, E);
  k_norm<<<gE, TB, 0, stream>>>(ei_ib,  ei_ib + E,  nullptr, deg + 3 * N, norm_ib,  E);

  // ---- 2. weight prep ----
  k_transpose<<<cdiv(128 * 128, TB), TB, 0, stream>>>(lin1_w,   Wt_lin1,  128, 128);
  k_transpose<<<cdiv(128 * 128, TB), TB, 0, stream>>>(ib1_ln_w, Wt_ib1ln, 128, 128);
  k_transpose<<<cdiv(128 * 128, TB), TB, 0, stream>>>(ib2_ln_w, Wt_ib2ln, 128, 128);
  k_transpose<<<cdiv(128 * 256, TB), TB, 0, stream>>>(conv1_w,  Wt_conv1, 128, 256);
  k_transpose<<<cdiv(64 * 128, TB),  TB, 0, stream>>>(lin2_w,   Wt_lin2,  64, 128);
  k_bias3<<<1, 128, 0, stream>>>(ib1_ln_b, ib1_c1_b, ib1_c2_b, bias1, 128);
  k_bias3<<<1, 128, 0, stream>>>(ib2_ln_b, ib2_c1_b, ib2_c2_b, bias2, 128);

  // ---- 3. stage 1 ----
  // symx_lin = x @ lin1^T
  k_gemm<128, 128, 128, false, false><<<gG, TB, 0, stream>>>(x, nullptr, Wt_lin1, nullptr, B0, N);
  // hbase = x @ ib1_ln^T + (ln_b + c1_b + c2_b)
  k_gemm<128, 128, 128, false, false><<<gG, TB, 0, stream>>>(x, nullptr, Wt_ib1ln, bias1, B2, N);
  // digcn 1: B2 += scatter(x @ ib1_c1_w, w_ib)
  k_gemm<128, 128, 128, false, false><<<gG, TB, 0, stream>>>(x, nullptr, ib1_c1_w, nullptr, B3, N);
  k_scatter<128><<<gS128, TB, 0, stream>>>(B3, ei_ib, ei_ib + E, w_ib, B2, E);
  // digcn 2: B2 += scatter(x @ ib1_c2_w, w_ib2)
  k_gemm<128, 128, 128, false, false><<<gG, TB, 0, stream>>>(x, nullptr, ib1_c2_w, nullptr, B3, N);
  k_scatter<128><<<gS128, TB, 0, stream>>>(B3, ei_ib2, ei_ib2 + E, w_ib2, B2, E);
  // symx_agg = 3 dgcn scatters of symx_lin
  hipMemsetAsync(B1, 0, (size_t)N * 128 * sizeof(float), stream);
  k_scatter<128><<<gS128, TB, 0, stream>>>(B0, ei_sym, ei_sym + E, norm_sym, B1, E);
  k_scatter<128><<<gS128, TB, 0, stream>>>(B0, ei_in,  ei_in + E,  norm_in,  B1, E);
  k_scatter<128><<<gS128, TB, 0, stream>>>(B0, ei_out, ei_out + E, norm_out, B1, E);

  // ---- 4. conv1: h = relu(concat(B2, B1) @ conv1^T + b) -> B0 ----
  k_gemm<256, 128, 128, false, true><<<gG, TB, 0, stream>>>(B2, B1, Wt_conv1, conv1_b, B0, N);

  // ---- 5. stage 2 (inputs h=B0) ----
  k_gemm<128, 128, 128, false, false><<<gG, TB, 0, stream>>>(B0, nullptr, Wt_ib2ln, bias2, B2, N);
  k_gemm<128, 128, 128, false, false><<<gG, TB, 0, stream>>>(B0, nullptr, ib2_c1_w, nullptr, B3, N);
  k_scatter<128><<<gS128, TB, 0, stream>>>(B3, ei_ib, ei_ib + E, w_ib, B2, E);
  k_gemm<128, 128, 128, false, false><<<gG, TB, 0, stream>>>(B0, nullptr, ib2_c2_w, nullptr, B3, N);
  k_scatter<128><<<gS128, TB, 0, stream>>>(B3, ei_ib2, ei_ib2 + E, w_ib2, B2, E);

  // ---- 6. final: symx2 = relu(B2) @ lin2^T -> B1[:, :64] ----
  k_gemm<128, 128, 64, true, false><<<gG, TB, 0, stream>>>(B2, nullptr, Wt_lin2, nullptr, B1, N);

  // ---- 7. out = 3 dgcn scatters of symx2 (64-dim) into d_out ----
  float* out = (float*)d_out;
  hipMemsetAsync(out, 0, (size_t)out_size * sizeof(float), stream);
  k_scatter<64><<<gS64, TB, 0, stream>>>(B1, ei_ib,  ei_ib + E,  norm_ib,  out, E);
  k_scatter<64><<<gS64, TB, 0, stream>>>(B1, ei_in,  ei_in + E,  norm_in,  out, E);
  k_scatter<64><<<gS64, TB, 0, stream>>>(B1, ei_out, ei_out + E, norm_out, out, E);
}

// Round 2
// 1750.995 us; speedup vs baseline: 6.9069x; 6.9069x over previous
//
#include <hip/hip_runtime.h>

// ---------------------------------------------------------------------------
// DiGCN_IB_3MixBN_SymCat — round 2: CSR gather instead of atomic scatter.
// N=50000, E=800000 per set (5 sets), dims 128/128/64, f32.
//
// Per call:
//   1. weighted degrees -> rsqrt (4 normalized sets)
//   2. CSR build by dst for 5 edge sets (count, scan, fill {src, w} entries)
//   3. 9 LDS-tiled f32 GEMMs (unchanged from round 1)
//   4. 6 gather kernels (fused bases / multi-edge-set / ReLU epilogues)
// ---------------------------------------------------------------------------

static inline int cdiv(int a, int b) { return (a + b - 1) / b; }

struct __align__(8) Ent { int s; float w; };

__global__ void k_deg(const int* __restrict__ src, const float* __restrict__ w,
                      float* __restrict__ deg, int E) {
  int e = blockIdx.x * blockDim.x + threadIdx.x;
  if (e < E) unsafeAtomicAdd(&deg[src[e]], w ? w[e] : 1.0f);
}

__global__ void k_rsqrt(float* __restrict__ d, int n) {
  int i = blockIdx.x * blockDim.x + threadIdx.x;
  if (i < n) {
    float v = d[i];
    d[i] = (v > 0.0f) ? rsqrtf(v) : 0.0f;
  }
}

__global__ void k_count(const int* __restrict__ dst, int* __restrict__ cnt, int E) {
  int e = blockIdx.x * blockDim.x + threadIdx.x;
  if (e < E) atomicAdd(&cnt[dst[e]], 1);
}

// one block per set: exclusive scan cnt[set][0..N) -> rptr[set][0..N]
__global__ __launch_bounds__(1024) void k_scan(const int* __restrict__ cnt,
                                               int* __restrict__ rptr, int N) {
  const int* c = cnt + (size_t)blockIdx.x * N;
  int* r = rptr + (size_t)blockIdx.x * (N + 1);
  __shared__ int lds[1024];
  int carry = 0;
  for (int base = 0; base < N; base += 1024) {
    int i = base + threadIdx.x;
    int v = (i < N) ? c[i] : 0;
    lds[threadIdx.x] = v;
    __syncthreads();
#pragma unroll
    for (int d = 1; d < 1024; d <<= 1) {
      int t = (threadIdx.x >= d) ? lds[threadIdx.x - d] : 0;
      __syncthreads();
      lds[threadIdx.x] += t;
      __syncthreads();
    }
    if (i < N) r[i] = carry + lds[threadIdx.x] - v;   // exclusive
    carry += lds[1023];
    __syncthreads();
  }
  if (threadIdx.x == 0) r[N] = carry;
}

__global__ void k_cursor(const int* __restrict__ rptr, int* __restrict__ cur, int N) {
  int i = blockIdx.x * blockDim.x + threadIdx.x;
  int set = blockIdx.y;
  if (i < N) cur[(size_t)set * N + i] = rptr[(size_t)set * (N + 1) + i];
}

// generic fill: ent[pos] = {src, dinv? dinv[s]*w*dinv[d] : w}
__global__ void k_fill(const int* __restrict__ src, const int* __restrict__ dst,
                       const float* __restrict__ w, const float* __restrict__ dinv,
                       int* __restrict__ cur, Ent* __restrict__ ent, int E) {
  int e = blockIdx.x * blockDim.x + threadIdx.x;
  if (e >= E) return;
  int s = src[e], d = dst[e];
  float ww = w ? w[e] : 1.0f;
  float nw = dinv ? dinv[s] * ww * dinv[d] : ww;
  int pos = atomicAdd(&cur[d], 1);
  ent[pos].s = s;
  ent[pos].w = nw;
}

// ib set: need both raw-w and dgcn-norm entry arrays, same permutation
__global__ void k_fill_ib(const int* __restrict__ src, const int* __restrict__ dst,
                          const float* __restrict__ w, const float* __restrict__ dinv,
                          int* __restrict__ cur, Ent* __restrict__ eraw,
                          Ent* __restrict__ enrm, int E) {
  int e = blockIdx.x * blockDim.x + threadIdx.x;
  if (e >= E) return;
  int s = src[e], d = dst[e];
  int pos = atomicAdd(&cur[d], 1);
  eraw[pos].s = s; eraw[pos].w = w[e];
  enrm[pos].s = s; enrm[pos].w = dinv[s] * dinv[d];
}

__global__ void k_bias3(const float* __restrict__ a, const float* __restrict__ b,
                        const float* __restrict__ c, float* __restrict__ o, int n) {
  int i = blockIdx.x * blockDim.x + threadIdx.x;
  if (i < n) o[i] = a[i] + b[i] + c[i];
}

__global__ void k_transpose(const float* __restrict__ s, float* __restrict__ d,
                            int R, int C) {
  int i = blockIdx.x * blockDim.x + threadIdx.x;
  if (i < R * C) {
    int r = i / C, c = i % C;
    d[(size_t)c * R + r] = s[i];
  }
}

// out[row] = act( (BASE? base[row]:0) + sum over up to 3 CSR sets of w*X[src] )
// one wave per row; M=128 -> float2/lane, M=64 -> float/lane.
template <int M, int NS, bool RELU, bool BASE>
__global__ __launch_bounds__(256) void k_gather(
    const float* __restrict__ X, const float* __restrict__ base,
    float* __restrict__ out,
    const int* __restrict__ rp0, const Ent* __restrict__ e0,
    const int* __restrict__ rp1, const Ent* __restrict__ e1,
    const int* __restrict__ rp2, const Ent* __restrict__ e2,
    int N) {
  int row = blockIdx.x * 4 + (threadIdx.x >> 6);
  if (row >= N) return;
  int lane = threadIdx.x & 63;
  if constexpr (M == 128) {
    float2 acc = make_float2(0.0f, 0.0f);
    if constexpr (BASE)
      acc = *reinterpret_cast<const float2*>(base + (size_t)row * 128 + lane * 2);
    auto doSet = [&](const int* __restrict__ rp, const Ent* __restrict__ ee) {
      int i = rp[row], en = rp[row + 1];
      for (; i + 1 < en; i += 2) {
        Ent a = ee[i], b = ee[i + 1];
        float2 va = *reinterpret_cast<const float2*>(X + (size_t)a.s * 128 + lane * 2);
        float2 vb = *reinterpret_cast<const float2*>(X + (size_t)b.s * 128 + lane * 2);
        acc.x = fmaf(a.w, va.x, acc.x); acc.y = fmaf(a.w, va.y, acc.y);
        acc.x = fmaf(b.w, vb.x, acc.x); acc.y = fmaf(b.w, vb.y, acc.y);
      }
      if (i < en) {
        Ent a = ee[i];
        float2 va = *reinterpret_cast<const float2*>(X + (size_t)a.s * 128 + lane * 2);
        acc.x = fmaf(a.w, va.x, acc.x); acc.y = fmaf(a.w, va.y, acc.y);
      }
    };
    doSet(rp0, e0);
    if constexpr (NS > 1) doSet(rp1, e1);
    if constexpr (NS > 2) doSet(rp2, e2);
    if constexpr (RELU) { acc.x = fmaxf(acc.x, 0.0f); acc.y = fmaxf(acc.y, 0.0f); }
    *reinterpret_cast<float2*>(out + (size_t)row * 128 + lane * 2) = acc;
  } else {
    float acc = 0.0f;
    if constexpr (BASE) acc = base[(size_t)row * M + lane];
    auto doSet = [&](const int* __restrict__ rp, const Ent* __restrict__ ee) {
      int i = rp[row], en = rp[row + 1];
      for (; i + 1 < en; i += 2) {
        Ent a = ee[i], b = ee[i + 1];
        float va = X[(size_t)a.s * M + lane];
        float vb = X[(size_t)b.s * M + lane];
        acc = fmaf(a.w, va, acc);
        acc = fmaf(b.w, vb, acc);
      }
      if (i < en) { Ent a = ee[i]; acc = fmaf(a.w, X[(size_t)a.s * M + lane], acc); }
    };
    doSet(rp0, e0);
    if constexpr (NS > 1) doSet(rp1, e1);
    if constexpr (NS > 2) doSet(rp2, e2);
    if constexpr (RELU) acc = fmaxf(acc, 0.0f);
    out[(size_t)row * M + lane] = acc;
  }
}

// C[n][m] = act( sum_k A[n][k]*Wt[k][m] + bias[m] ), A split at K1 (A1|A2)
template <int K, int K1, int M, bool RELU_A, bool RELU_OUT>
__global__ __launch_bounds__(256) void k_gemm(
    const float* __restrict__ A1, const float* __restrict__ A2,
    const float* __restrict__ Wt, const float* __restrict__ bias,
    float* __restrict__ C, int N) {
  __shared__ float lds_a[64][65];
  __shared__ float lds_w[64][M];
  constexpr int JM = M / 16;
  float acc[4][JM];
#pragma unroll
  for (int i = 0; i < 4; i++)
#pragma unroll
    for (int j = 0; j < JM; j++) acc[i][j] = 0.0f;

  const int tid = threadIdx.x;
  const int mg = tid & 15;
  const int ng = tid >> 4;
  const int node_base = blockIdx.x * 64;
  const int lk = tid & 63;
  const int ln0 = tid >> 6;

  for (int k0 = 0; k0 < K; k0 += 64) {
    const float* A;
    int lda, kk0;
    if (k0 < K1) { A = A1; lda = K1; kk0 = k0; }
    else         { A = A2; lda = K - K1; kk0 = k0 - K1; }
#pragma unroll
    for (int i = 0; i < 16; i++) {
      int ln = i * 4 + ln0;
      int node = node_base + ln;
      float v = 0.0f;
      if (node < N) v = A[(size_t)node * lda + kk0 + lk];
      if (RELU_A) v = fmaxf(v, 0.0f);
      lds_a[ln][lk] = v;
    }
    for (int idx = tid; idx < 64 * M; idx += 256)
      lds_w[idx / M][idx % M] = Wt[(size_t)(k0 + idx / M) * M + (idx % M)];
    __syncthreads();
#pragma unroll 4
    for (int kk = 0; kk < 64; kk++) {
      float a[4];
#pragma unroll
      for (int i = 0; i < 4; i++) a[i] = lds_a[ng * 4 + i][kk];
#pragma unroll
      for (int j = 0; j < JM; j++) {
        float wv = lds_w[kk][mg + 16 * j];
#pragma unroll
        for (int i = 0; i < 4; i++) acc[i][j] = fmaf(a[i], wv, acc[i][j]);
      }
    }
    __syncthreads();
  }
#pragma unroll
  for (int i = 0; i < 4; i++) {
    int node = node_base + ng * 4 + i;
    if (node >= N) continue;
#pragma unroll
    for (int j = 0; j < JM; j++) {
      float v = acc[i][j];
      int m = mg + 16 * j;
      if (bias) v += bias[m];
      if (RELU_OUT) v = fmaxf(v, 0.0f);
      C[(size_t)node * M + m] = v;
    }
  }
}

extern "C" void kernel_launch(void* const* d_in, const int* in_sizes, int n_in,
                              void* d_out, int out_size, void* d_ws, size_t ws_size,
                              hipStream_t stream) {
  const float* x        = (const float*)d_in[0];
  const int*   ei_sym   = (const int*)d_in[1];
  const int*   ei_in    = (const int*)d_in[2];
  const float* in_w     = (const float*)d_in[3];
  const int*   ei_out   = (const int*)d_in[4];
  const float* out_w    = (const float*)d_in[5];
  const int*   ei_ib    = (const int*)d_in[6];
  const float* w_ib     = (const float*)d_in[7];
  const int*   ei_ib2   = (const int*)d_in[8];
  const float* w_ib2    = (const float*)d_in[9];
  const float* lin1_w   = (const float*)d_in[10];
  const float* lin2_w   = (const float*)d_in[11];
  const float* ib1_ln_w = (const float*)d_in[12];
  const float* ib1_ln_b = (const float*)d_in[13];
  const float* ib1_c1_w = (const float*)d_in[14];
  const float* ib1_c1_b = (const float*)d_in[15];
  const float* ib1_c2_w = (const float*)d_in[16];
  const float* ib1_c2_b = (const float*)d_in[17];
  const float* ib2_ln_w = (const float*)d_in[18];
  const float* ib2_ln_b = (const float*)d_in[19];
  const float* ib2_c1_w = (const float*)d_in[20];
  const float* ib2_c1_b = (const float*)d_in[21];
  const float* ib2_c2_w = (const float*)d_in[22];
  const float* ib2_c2_b = (const float*)d_in[23];
  const float* conv1_w  = (const float*)d_in[24];
  const float* conv1_b  = (const float*)d_in[25];

  const int N = in_sizes[0] / 128;
  const int E = in_sizes[1] / 2;

  float* ws = (float*)d_ws;
  size_t off = 0;
  auto alloc = [&](size_t n) {
    float* p = ws + off;
    off += (n + 63) & ~size_t(63);
    return p;
  };
  float* B0 = alloc((size_t)N * 128);
  float* B1 = alloc((size_t)N * 128);
  float* B2 = alloc((size_t)N * 128);
  float* B3 = alloc((size_t)N * 128);
  // CSR entry arrays (8B per edge): sym, in, out, ib_raw, ib_norm, ib2
  Ent* ent_sym  = (Ent*)alloc((size_t)E * 2);
  Ent* ent_in   = (Ent*)alloc((size_t)E * 2);
  Ent* ent_out  = (Ent*)alloc((size_t)E * 2);
  Ent* ent_ibr  = (Ent*)alloc((size_t)E * 2);
  Ent* ent_ibn  = (Ent*)alloc((size_t)E * 2);
  Ent* ent_ib2  = (Ent*)alloc((size_t)E * 2);
  int* rptr = (int*)alloc(5 * (size_t)(N + 1));  // [5][N+1]: sym,in,out,ib,ib2
  int* cnt  = (int*)alloc(5 * (size_t)N);        // counts -> cursors
  float* deg = alloc(4 * (size_t)N);             // dinv: sym,in,out,ib
  float* Wt_lin1  = alloc(128 * 128);
  float* Wt_ib1ln = alloc(128 * 128);
  float* Wt_ib2ln = alloc(128 * 128);
  float* Wt_conv1 = alloc(256 * 128);
  float* Wt_lin2  = alloc(128 * 64);
  float* bias1 = alloc(128);
  float* bias2 = alloc(128);

  const int TB = 256;
  const int gE = cdiv(E, TB);
  const int gG = cdiv(N, 64);
  const int gR = cdiv(N, 4);   // gather grid: 4 rows/block

  const int* rp_sym = rptr + 0 * (N + 1);
  const int* rp_in  = rptr + 1 * (N + 1);
  const int* rp_out = rptr + 2 * (N + 1);
  const int* rp_ib  = rptr + 3 * (N + 1);
  const int* rp_ib2 = rptr + 4 * (N + 1);

  // ---- 1. degrees -> dinv ----
  hipMemsetAsync(deg, 0, 4 * (size_t)N * sizeof(float), stream);
  hipMemsetAsync(cnt, 0, 5 * (size_t)N * sizeof(int), stream);
  k_deg<<<gE, TB, 0, stream>>>(ei_sym, nullptr, deg + 0 * N, E);
  k_deg<<<gE, TB, 0, stream>>>(ei_in,  in_w,    deg + 1 * N, E);
  k_deg<<<gE, TB, 0, stream>>>(ei_out, out_w,   deg + 2 * N, E);
  k_deg<<<gE, TB, 0, stream>>>(ei_ib,  nullptr, deg + 3 * N, E);
  k_rsqrt<<<cdiv(4 * N, TB), TB, 0, stream>>>(deg, 4 * N);

  // ---- 2. CSR build ----
  k_count<<<gE, TB, 0, stream>>>(ei_sym + E, cnt + 0 * N, E);
  k_count<<<gE, TB, 0, stream>>>(ei_in  + E, cnt + 1 * N, E);
  k_count<<<gE, TB, 0, stream>>>(ei_out + E, cnt + 2 * N, E);
  k_count<<<gE, TB, 0, stream>>>(ei_ib  + E, cnt + 3 * N, E);
  k_count<<<gE, TB, 0, stream>>>(ei_ib2 + E, cnt + 4 * N, E);
  k_scan<<<5, 1024, 0, stream>>>(cnt, rptr, N);
  {
    dim3 g(cdiv(N, TB), 5);
    k_cursor<<<g, TB, 0, stream>>>(rptr, cnt, N);
  }
  k_fill<<<gE, TB, 0, stream>>>(ei_sym, ei_sym + E, nullptr, deg + 0 * N, cnt + 0 * N, ent_sym, E);
  k_fill<<<gE, TB, 0, stream>>>(ei_in,  ei_in + E,  in_w,    deg + 1 * N, cnt + 1 * N, ent_in,  E);
  k_fill<<<gE, TB, 0, stream>>>(ei_out, ei_out + E, out_w,   deg + 2 * N, cnt + 2 * N, ent_out, E);
  k_fill_ib<<<gE, TB, 0, stream>>>(ei_ib, ei_ib + E, w_ib, deg + 3 * N, cnt + 3 * N, ent_ibr, ent_ibn, E);
  k_fill<<<gE, TB, 0, stream>>>(ei_ib2, ei_ib2 + E, w_ib2, nullptr, cnt + 4 * N, ent_ib2, E);

  // ---- 3. weight prep ----
  k_transpose<<<cdiv(128 * 128, TB), TB, 0, stream>>>(lin1_w,   Wt_lin1,  128, 128);
  k_transpose<<<cdiv(128 * 128, TB), TB, 0, stream>>>(ib1_ln_w, Wt_ib1ln, 128, 128);
  k_transpose<<<cdiv(128 * 128, TB), TB, 0, stream>>>(ib2_ln_w, Wt_ib2ln, 128, 128);
  k_transpose<<<cdiv(128 * 256, TB), TB, 0, stream>>>(conv1_w,  Wt_conv1, 128, 256);
  k_transpose<<<cdiv(64 * 128, TB),  TB, 0, stream>>>(lin2_w,   Wt_lin2,  64, 128);
  k_bias3<<<1, 128, 0, stream>>>(ib1_ln_b, ib1_c1_b, ib1_c2_b, bias1, 128);
  k_bias3<<<1, 128, 0, stream>>>(ib2_ln_b, ib2_c1_b, ib2_c2_b, bias2, 128);

  // ---- 4. stage 1 ----
  k_gemm<128, 128, 128, false, false><<<gG, TB, 0, stream>>>(x, nullptr, Wt_lin1, nullptr, B0, N);   // symx
  k_gemm<128, 128, 128, false, false><<<gG, TB, 0, stream>>>(x, nullptr, Wt_ib1ln, bias1, B2, N);    // hbase
  k_gemm<128, 128, 128, false, false><<<gG, TB, 0, stream>>>(x, nullptr, ib1_c1_w, nullptr, B3, N);  // xw1
  k_gather<128, 1, false, true><<<gR, TB, 0, stream>>>(B3, B2, B2, rp_ib, ent_ibr,
                                                       nullptr, nullptr, nullptr, nullptr, N);
  k_gemm<128, 128, 128, false, false><<<gG, TB, 0, stream>>>(x, nullptr, ib1_c2_w, nullptr, B3, N);  // xw2
  k_gather<128, 1, false, true><<<gR, TB, 0, stream>>>(B3, B2, B2, rp_ib2, ent_ib2,
                                                       nullptr, nullptr, nullptr, nullptr, N);
  // symx aggregation: 3 sets fused
  k_gather<128, 3, false, false><<<gR, TB, 0, stream>>>(B0, nullptr, B1,
                                                        rp_sym, ent_sym, rp_in, ent_in, rp_out, ent_out, N);
  // conv1: h = relu(concat(B2,B1) @ conv1^T + b) -> B3
  k_gemm<256, 128, 128, false, true><<<gG, TB, 0, stream>>>(B2, B1, Wt_conv1, conv1_b, B3, N);

  // ---- 5. stage 2 (h = B3) ----
  k_gemm<128, 128, 128, false, false><<<gG, TB, 0, stream>>>(B3, nullptr, Wt_ib2ln, bias2, B0, N);
  k_gemm<128, 128, 128, false, false><<<gG, TB, 0, stream>>>(B3, nullptr, ib2_c1_w, nullptr, B2, N);
  k_gather<128, 1, false, true><<<gR, TB, 0, stream>>>(B2, B0, B0, rp_ib, ent_ibr,
                                                       nullptr, nullptr, nullptr, nullptr, N);
  k_gemm<128, 128, 128, false, false><<<gG, TB, 0, stream>>>(B3, nullptr, ib2_c2_w, nullptr, B2, N);
  k_gather<128, 1, true, true><<<gR, TB, 0, stream>>>(B2, B0, B0, rp_ib2, ent_ib2,
                                                      nullptr, nullptr, nullptr, nullptr, N);  // relu

  // ---- 6. final: symx2 = B0 @ lin2^T -> B1 (64-dim) ----
  k_gemm<128, 128, 64, false, false><<<gG, TB, 0, stream>>>(B0, nullptr, Wt_lin2, nullptr, B1, N);

  // ---- 7. out = 3 dgcn gathers (64-dim, fused) ----
  k_gather<64, 3, false, false><<<gR, TB, 0, stream>>>(B1, nullptr, (float*)d_out,
                                                       rp_ib, ent_ibn, rp_in, ent_in, rp_out, ent_out, N);
}

// Round 3
// 1484.011 us; speedup vs baseline: 8.1495x; 1.1799x over previous
//
#include <hip/hip_runtime.h>

// ---------------------------------------------------------------------------
// DiGCN_IB_3MixBN_SymCat — round 3: bf16 intermediates.
// All gathered/GEMM'd node matrices stored bf16 (f32 accumulate everywhere);
// CSR gather reads 256B/row instead of 512B. f32 only for x input, weights,
// edge norms, and final output.
// ---------------------------------------------------------------------------

static inline int cdiv(int a, int b) { return (a + b - 1) / b; }

struct __align__(8) Ent { int s; float w; };

__device__ __forceinline__ float b2f(uint u)  { return __uint_as_float(u << 16); }
__device__ __forceinline__ float b2fh(uint u) { return __uint_as_float(u & 0xFFFF0000u); }
__device__ __forceinline__ ushort f2b(float f) {
  uint u = __float_as_uint(f);
  return (ushort)((u + 0x7FFFu + ((u >> 16) & 1u)) >> 16);
}

__global__ void k_cvt(const float* __restrict__ s, ushort* __restrict__ d, int n) {
  int i = (blockIdx.x * blockDim.x + threadIdx.x) * 4;
  if (i >= n) return;
  float4 v = *reinterpret_cast<const float4*>(s + i);
  ushort4 o;
  o.x = f2b(v.x); o.y = f2b(v.y); o.z = f2b(v.z); o.w = f2b(v.w);
  *reinterpret_cast<ushort4*>(d + i) = o;
}

// one edge pass: weighted degree over src (optional) + count over dst
__global__ void k_degcnt(const int* __restrict__ src, const int* __restrict__ dst,
                         const float* __restrict__ w, float* __restrict__ deg,
                         int* __restrict__ cnt, int E) {
  int e = blockIdx.x * blockDim.x + threadIdx.x;
  if (e >= E) return;
  if (deg) unsafeAtomicAdd(&deg[src[e]], w ? w[e] : 1.0f);
  atomicAdd(&cnt[dst[e]], 1);
}

__global__ void k_rsqrt(float* __restrict__ d, int n) {
  int i = blockIdx.x * blockDim.x + threadIdx.x;
  if (i < n) {
    float v = d[i];
    d[i] = (v > 0.0f) ? rsqrtf(v) : 0.0f;
  }
}

// one block per set: exclusive scan cnt[set][0..N) -> rptr[set][0..N]
__global__ __launch_bounds__(1024) void k_scan(const int* __restrict__ cnt,
                                               int* __restrict__ rptr, int N) {
  const int* c = cnt + (size_t)blockIdx.x * N;
  int* r = rptr + (size_t)blockIdx.x * (N + 1);
  __shared__ int lds[1024];
  int carry = 0;
  for (int base = 0; base < N; base += 1024) {
    int i = base + threadIdx.x;
    int v = (i < N) ? c[i] : 0;
    lds[threadIdx.x] = v;
    __syncthreads();
#pragma unroll
    for (int d = 1; d < 1024; d <<= 1) {
      int t = (threadIdx.x >= d) ? lds[threadIdx.x - d] : 0;
      __syncthreads();
      lds[threadIdx.x] += t;
      __syncthreads();
    }
    if (i < N) r[i] = carry + lds[threadIdx.x] - v;   // exclusive
    carry += lds[1023];
    __syncthreads();
  }
  if (threadIdx.x == 0) r[N] = carry;
}

__global__ void k_cursor(const int* __restrict__ rptr, int* __restrict__ cur, int N) {
  int i = blockIdx.x * blockDim.x + threadIdx.x;
  int set = blockIdx.y;
  if (i < N) cur[(size_t)set * N + i] = rptr[(size_t)set * (N + 1) + i];
}

__global__ void k_fill(const int* __restrict__ src, const int* __restrict__ dst,
                       const float* __restrict__ w, const float* __restrict__ dinv,
                       int* __restrict__ cur, Ent* __restrict__ ent, int E) {
  int e = blockIdx.x * blockDim.x + threadIdx.x;
  if (e >= E) return;
  int s = src[e], d = dst[e];
  float ww = w ? w[e] : 1.0f;
  float nw = dinv ? dinv[s] * ww * dinv[d] : ww;
  int pos = atomicAdd(&cur[d], 1);
  ent[pos].s = s;
  ent[pos].w = nw;
}

__global__ void k_fill_ib(const int* __restrict__ src, const int* __restrict__ dst,
                          const float* __restrict__ w, const float* __restrict__ dinv,
                          int* __restrict__ cur, Ent* __restrict__ eraw,
                          Ent* __restrict__ enrm, int E) {
  int e = blockIdx.x * blockDim.x + threadIdx.x;
  if (e >= E) return;
  int s = src[e], d = dst[e];
  int pos = atomicAdd(&cur[d], 1);
  eraw[pos].s = s; eraw[pos].w = w[e];
  enrm[pos].s = s; enrm[pos].w = dinv[s] * dinv[d];
}

__global__ void k_bias3(const float* __restrict__ a, const float* __restrict__ b,
                        const float* __restrict__ c, float* __restrict__ o, int n) {
  int i = blockIdx.x * blockDim.x + threadIdx.x;
  if (i < n) o[i] = a[i] + b[i] + c[i];
}

__global__ void k_transpose(const float* __restrict__ s, float* __restrict__ d,
                            int R, int C) {
  int i = blockIdx.x * blockDim.x + threadIdx.x;
  if (i < R * C) {
    int r = i / C, c = i % C;
    d[(size_t)c * R + r] = s[i];
  }
}

// out[row] = act( (BASE? base[row]:0) + sum over NS CSR sets of w*X[src] )
// X/base bf16; f32 accumulate; out bf16 (or f32 when OUTF32).
// one wave per row: M=128 -> 2 dims/lane (uint load), M=64 -> 1 dim/lane.
template <int M, int NS, bool RELU, bool BASE, bool OUTF32>
__global__ __launch_bounds__(256) void k_gather(
    const ushort* __restrict__ X, const ushort* __restrict__ base,
    void* __restrict__ outv,
    const int* __restrict__ rp0, const Ent* __restrict__ e0,
    const int* __restrict__ rp1, const Ent* __restrict__ e1,
    const int* __restrict__ rp2, const Ent* __restrict__ e2,
    int N) {
  int row = blockIdx.x * 4 + (threadIdx.x >> 6);
  if (row >= N) return;
  int lane = threadIdx.x & 63;

  if constexpr (M == 128) {
    float ax = 0.0f, ay = 0.0f;
    if constexpr (BASE) {
      uint b = *reinterpret_cast<const uint*>(base + (size_t)row * 128 + lane * 2);
      ax = b2f(b); ay = b2fh(b);
    }
    auto doSet = [&](const int* __restrict__ rp, const Ent* __restrict__ ee) {
      int i = rp[row], en = rp[row + 1];
      for (; i + 4 <= en; i += 4) {
        Ent a0 = ee[i], a1 = ee[i + 1], a2 = ee[i + 2], a3 = ee[i + 3];
        uint b0 = *reinterpret_cast<const uint*>(X + (size_t)a0.s * 128 + lane * 2);
        uint b1 = *reinterpret_cast<const uint*>(X + (size_t)a1.s * 128 + lane * 2);
        uint b2 = *reinterpret_cast<const uint*>(X + (size_t)a2.s * 128 + lane * 2);
        uint b3 = *reinterpret_cast<const uint*>(X + (size_t)a3.s * 128 + lane * 2);
        ax = fmaf(a0.w, b2f(b0), ax); ay = fmaf(a0.w, b2fh(b0), ay);
        ax = fmaf(a1.w, b2f(b1), ax); ay = fmaf(a1.w, b2fh(b1), ay);
        ax = fmaf(a2.w, b2f(b2), ax); ay = fmaf(a2.w, b2fh(b2), ay);
        ax = fmaf(a3.w, b2f(b3), ax); ay = fmaf(a3.w, b2fh(b3), ay);
      }
      for (; i < en; ++i) {
        Ent a = ee[i];
        uint b = *reinterpret_cast<const uint*>(X + (size_t)a.s * 128 + lane * 2);
        ax = fmaf(a.w, b2f(b), ax); ay = fmaf(a.w, b2fh(b), ay);
      }
    };
    doSet(rp0, e0);
    if constexpr (NS > 1) doSet(rp1, e1);
    if constexpr (NS > 2) doSet(rp2, e2);
    if constexpr (RELU) { ax = fmaxf(ax, 0.0f); ay = fmaxf(ay, 0.0f); }
    if constexpr (OUTF32) {
      float2* o = reinterpret_cast<float2*>((float*)outv + (size_t)row * 128 + lane * 2);
      *o = make_float2(ax, ay);
    } else {
      uint pk = (uint)f2b(ax) | ((uint)f2b(ay) << 16);
      *reinterpret_cast<uint*>((ushort*)outv + (size_t)row * 128 + lane * 2) = pk;
    }
  } else {  // M == 64
    float acc = 0.0f;
    if constexpr (BASE) acc = b2f((uint)base[(size_t)row * 64 + lane]);
    auto doSet = [&](const int* __restrict__ rp, const Ent* __restrict__ ee) {
      int i = rp[row], en = rp[row + 1];
      for (; i + 4 <= en; i += 4) {
        Ent a0 = ee[i], a1 = ee[i + 1], a2 = ee[i + 2], a3 = ee[i + 3];
        float v0 = b2f((uint)X[(size_t)a0.s * 64 + lane]);
        float v1 = b2f((uint)X[(size_t)a1.s * 64 + lane]);
        float v2 = b2f((uint)X[(size_t)a2.s * 64 + lane]);
        float v3 = b2f((uint)X[(size_t)a3.s * 64 + lane]);
        acc = fmaf(a0.w, v0, acc); acc = fmaf(a1.w, v1, acc);
        acc = fmaf(a2.w, v2, acc); acc = fmaf(a3.w, v3, acc);
      }
      for (; i < en; ++i) {
        Ent a = ee[i];
        acc = fmaf(a.w, b2f((uint)X[(size_t)a.s * 64 + lane]), acc);
      }
    };
    doSet(rp0, e0);
    if constexpr (NS > 1) doSet(rp1, e1);
    if constexpr (NS > 2) doSet(rp2, e2);
    if constexpr (RELU) acc = fmaxf(acc, 0.0f);
    if constexpr (OUTF32) {
      ((float*)outv)[(size_t)row * 64 + lane] = acc;
    } else {
      ((ushort*)outv)[(size_t)row * 64 + lane] = f2b(acc);
    }
  }
}

// C[n][m] = act( sum_k A[n][k]*Wt[k][m] + bias[m] ); A bf16, split at K1.
template <int K, int K1, int M, bool RELU_OUT>
__global__ __launch_bounds__(256) void k_gemm(
    const ushort* __restrict__ A1, const ushort* __restrict__ A2,
    const float* __restrict__ Wt, const float* __restrict__ bias,
    ushort* __restrict__ C, int N) {
  __shared__ float lds_a[64][65];
  __shared__ float lds_w[64][M];
  constexpr int JM = M / 16;
  float acc[4][JM];
#pragma unroll
  for (int i = 0; i < 4; i++)
#pragma unroll
    for (int j = 0; j < JM; j++) acc[i][j] = 0.0f;

  const int tid = threadIdx.x;
  const int mg = tid & 15;
  const int ng = tid >> 4;
  const int node_base = blockIdx.x * 64;
  const int lk = tid & 63;
  const int ln0 = tid >> 6;

  for (int k0 = 0; k0 < K; k0 += 64) {
    const ushort* A;
    int lda, kk0;
    if (k0 < K1) { A = A1; lda = K1; kk0 = k0; }
    else         { A = A2; lda = K - K1; kk0 = k0 - K1; }
#pragma unroll
    for (int i = 0; i < 16; i++) {
      int ln = i * 4 + ln0;
      int node = node_base + ln;
      float v = 0.0f;
      if (node < N) v = b2f((uint)A[(size_t)node * lda + kk0 + lk]);
      lds_a[ln][lk] = v;
    }
    for (int idx = tid; idx < 64 * M; idx += 256)
      lds_w[idx / M][idx % M] = Wt[(size_t)(k0 + idx / M) * M + (idx % M)];
    __syncthreads();
#pragma unroll 4
    for (int kk = 0; kk < 64; kk++) {
      float a[4];
#pragma unroll
      for (int i = 0; i < 4; i++) a[i] = lds_a[ng * 4 + i][kk];
#pragma unroll
      for (int j = 0; j < JM; j++) {
        float wv = lds_w[kk][mg + 16 * j];
#pragma unroll
        for (int i = 0; i < 4; i++) acc[i][j] = fmaf(a[i], wv, acc[i][j]);
      }
    }
    __syncthreads();
  }
#pragma unroll
  for (int i = 0; i < 4; i++) {
    int node = node_base + ng * 4 + i;
    if (node >= N) continue;
#pragma unroll
    for (int j = 0; j < JM; j++) {
      float v = acc[i][j];
      int m = mg + 16 * j;
      if (bias) v += bias[m];
      if (RELU_OUT) v = fmaxf(v, 0.0f);
      C[(size_t)node * M + m] = f2b(v);
    }
  }
}

extern "C" void kernel_launch(void* const* d_in, const int* in_sizes, int n_in,
                              void* d_out, int out_size, void* d_ws, size_t ws_size,
                              hipStream_t stream) {
  const float* x        = (const float*)d_in[0];
  const int*   ei_sym   = (const int*)d_in[1];
  const int*   ei_in    = (const int*)d_in[2];
  const float* in_w     = (const float*)d_in[3];
  const int*   ei_out   = (const int*)d_in[4];
  const float* out_w    = (const float*)d_in[5];
  const int*   ei_ib    = (const int*)d_in[6];
  const float* w_ib     = (const float*)d_in[7];
  const int*   ei_ib2   = (const int*)d_in[8];
  const float* w_ib2    = (const float*)d_in[9];
  const float* lin1_w   = (const float*)d_in[10];
  const float* lin2_w   = (const float*)d_in[11];
  const float* ib1_ln_w = (const float*)d_in[12];
  const float* ib1_ln_b = (const float*)d_in[13];
  const float* ib1_c1_w = (const float*)d_in[14];
  const float* ib1_c1_b = (const float*)d_in[15];
  const float* ib1_c2_w = (const float*)d_in[16];
  const float* ib1_c2_b = (const float*)d_in[17];
  const float* ib2_ln_w = (const float*)d_in[18];
  const float* ib2_ln_b = (const float*)d_in[19];
  const float* ib2_c1_w = (const float*)d_in[20];
  const float* ib2_c1_b = (const float*)d_in[21];
  const float* ib2_c2_w = (const float*)d_in[22];
  const float* ib2_c2_b = (const float*)d_in[23];
  const float* conv1_w  = (const float*)d_in[24];
  const float* conv1_b  = (const float*)d_in[25];

  const int N = in_sizes[0] / 128;
  const int E = in_sizes[1] / 2;

  // ---- workspace (byte allocator, 256B aligned) ----
  size_t off = 0;
  auto alloc = [&](size_t bytes) -> void* {
    void* p = (char*)d_ws + off;
    off = (off + bytes + 255) & ~size_t(255);
    return p;
  };
  ushort* xb = (ushort*)alloc((size_t)N * 128 * 2);
  ushort* B0 = (ushort*)alloc((size_t)N * 128 * 2);
  ushort* B1 = (ushort*)alloc((size_t)N * 128 * 2);
  ushort* B2 = (ushort*)alloc((size_t)N * 128 * 2);
  ushort* B3 = (ushort*)alloc((size_t)N * 128 * 2);
  Ent* ent_sym = (Ent*)alloc((size_t)E * 8);
  Ent* ent_in  = (Ent*)alloc((size_t)E * 8);
  Ent* ent_out = (Ent*)alloc((size_t)E * 8);
  Ent* ent_ibr = (Ent*)alloc((size_t)E * 8);
  Ent* ent_ibn = (Ent*)alloc((size_t)E * 8);
  Ent* ent_ib2 = (Ent*)alloc((size_t)E * 8);
  int* rptr = (int*)alloc(5 * (size_t)(N + 1) * 4);
  int* cnt  = (int*)alloc(5 * (size_t)N * 4);
  float* deg = (float*)alloc(4 * (size_t)N * 4);
  float* Wt_lin1  = (float*)alloc(128 * 128 * 4);
  float* Wt_ib1ln = (float*)alloc(128 * 128 * 4);
  float* Wt_ib2ln = (float*)alloc(128 * 128 * 4);
  float* Wt_conv1 = (float*)alloc(256 * 128 * 4);
  float* Wt_lin2  = (float*)alloc(128 * 64 * 4);
  float* bias1 = (float*)alloc(128 * 4);
  float* bias2 = (float*)alloc(128 * 4);

  const int TB = 256;
  const int gE = cdiv(E, TB);
  const int gG = cdiv(N, 64);
  const int gR = cdiv(N, 4);

  const int* rp_sym = rptr + 0 * (N + 1);
  const int* rp_in  = rptr + 1 * (N + 1);
  const int* rp_out = rptr + 2 * (N + 1);
  const int* rp_ib  = rptr + 3 * (N + 1);
  const int* rp_ib2 = rptr + 4 * (N + 1);

  // ---- 1. x -> bf16; degrees+counts ----
  k_cvt<<<cdiv(N * 128, TB * 4), TB, 0, stream>>>(x, xb, N * 128);
  hipMemsetAsync(deg, 0, 4 * (size_t)N * sizeof(float), stream);
  hipMemsetAsync(cnt, 0, 5 * (size_t)N * sizeof(int), stream);
  k_degcnt<<<gE, TB, 0, stream>>>(ei_sym, ei_sym + E, nullptr, deg + 0 * N, cnt + 0 * N, E);
  k_degcnt<<<gE, TB, 0, stream>>>(ei_in,  ei_in + E,  in_w,    deg + 1 * N, cnt + 1 * N, E);
  k_degcnt<<<gE, TB, 0, stream>>>(ei_out, ei_out + E, out_w,   deg + 2 * N, cnt + 2 * N, E);
  k_degcnt<<<gE, TB, 0, stream>>>(ei_ib,  ei_ib + E,  nullptr, deg + 3 * N, cnt + 3 * N, E);
  k_degcnt<<<gE, TB, 0, stream>>>(ei_ib2, ei_ib2 + E, nullptr, nullptr,     cnt + 4 * N, E);
  k_rsqrt<<<cdiv(4 * N, TB), TB, 0, stream>>>(deg, 4 * N);

  // ---- 2. CSR build ----
  k_scan<<<5, 1024, 0, stream>>>(cnt, rptr, N);
  {
    dim3 g(cdiv(N, TB), 5);
    k_cursor<<<g, TB, 0, stream>>>(rptr, cnt, N);
  }
  k_fill<<<gE, TB, 0, stream>>>(ei_sym, ei_sym + E, nullptr, deg + 0 * N, cnt + 0 * N, ent_sym, E);
  k_fill<<<gE, TB, 0, stream>>>(ei_in,  ei_in + E,  in_w,    deg + 1 * N, cnt + 1 * N, ent_in,  E);
  k_fill<<<gE, TB, 0, stream>>>(ei_out, ei_out + E, out_w,   deg + 2 * N, cnt + 2 * N, ent_out, E);
  k_fill_ib<<<gE, TB, 0, stream>>>(ei_ib, ei_ib + E, w_ib, deg + 3 * N, cnt + 3 * N, ent_ibr, ent_ibn, E);
  k_fill<<<gE, TB, 0, stream>>>(ei_ib2, ei_ib2 + E, w_ib2, nullptr, cnt + 4 * N, ent_ib2, E);

  // ---- 3. weight prep ----
  k_transpose<<<cdiv(128 * 128, TB), TB, 0, stream>>>(lin1_w,   Wt_lin1,  128, 128);
  k_transpose<<<cdiv(128 * 128, TB), TB, 0, stream>>>(ib1_ln_w, Wt_ib1ln, 128, 128);
  k_transpose<<<cdiv(128 * 128, TB), TB, 0, stream>>>(ib2_ln_w, Wt_ib2ln, 128, 128);
  k_transpose<<<cdiv(128 * 256, TB), TB, 0, stream>>>(conv1_w,  Wt_conv1, 128, 256);
  k_transpose<<<cdiv(64 * 128, TB),  TB, 0, stream>>>(lin2_w,   Wt_lin2,  64, 128);
  k_bias3<<<1, 128, 0, stream>>>(ib1_ln_b, ib1_c1_b, ib1_c2_b, bias1, 128);
  k_bias3<<<1, 128, 0, stream>>>(ib2_ln_b, ib2_c1_b, ib2_c2_b, bias2, 128);

  // ---- 4. stage 1 ----
  k_gemm<128, 128, 128, false><<<gG, TB, 0, stream>>>(xb, nullptr, Wt_lin1, nullptr, B0, N);   // symx
  k_gemm<128, 128, 128, false><<<gG, TB, 0, stream>>>(xb, nullptr, Wt_ib1ln, bias1, B2, N);    // hbase
  k_gemm<128, 128, 128, false><<<gG, TB, 0, stream>>>(xb, nullptr, ib1_c1_w, nullptr, B3, N);  // xw1
  k_gather<128, 1, false, true, false><<<gR, TB, 0, stream>>>(B3, B2, B2, rp_ib, ent_ibr,
                                                              nullptr, nullptr, nullptr, nullptr, N);
  k_gemm<128, 128, 128, false><<<gG, TB, 0, stream>>>(xb, nullptr, ib1_c2_w, nullptr, B3, N);  // xw2
  k_gather<128, 1, false, true, false><<<gR, TB, 0, stream>>>(B3, B2, B2, rp_ib2, ent_ib2,
                                                              nullptr, nullptr, nullptr, nullptr, N);
  // symx aggregation (3 sets fused)
  k_gather<128, 3, false, false, false><<<gR, TB, 0, stream>>>(B0, nullptr, B1,
                                                               rp_sym, ent_sym, rp_in, ent_in,
                                                               rp_out, ent_out, N);
  // conv1: h = relu(concat(B2,B1) @ conv1^T + b) -> B0
  k_gemm<256, 128, 128, true><<<gG, TB, 0, stream>>>(B2, B1, Wt_conv1, conv1_b, B0, N);

  // ---- 5. stage 2 (h = B0) ----
  k_gemm<128, 128, 128, false><<<gG, TB, 0, stream>>>(B0, nullptr, Wt_ib2ln, bias2, B2, N);
  k_gemm<128, 128, 128, false><<<gG, TB, 0, stream>>>(B0, nullptr, ib2_c1_w, nullptr, B3, N);
  k_gather<128, 1, false, true, false><<<gR, TB, 0, stream>>>(B3, B2, B2, rp_ib, ent_ibr,
                                                              nullptr, nullptr, nullptr, nullptr, N);
  k_gemm<128, 128, 128, false><<<gG, TB, 0, stream>>>(B0, nullptr, ib2_c2_w, nullptr, B3, N);
  k_gather<128, 1, true, true, false><<<gR, TB, 0, stream>>>(B3, B2, B2, rp_ib2, ent_ib2,
                                                             nullptr, nullptr, nullptr, nullptr, N);

  // ---- 6. symx2 = B2 @ lin2^T -> B1 (64-dim bf16) ----
  k_gemm<128, 128, 64, false><<<gG, TB, 0, stream>>>(B2, nullptr, Wt_lin2, nullptr, B1, N);

  // ---- 7. out (f32) = 3 dgcn gathers of B1 ----
  k_gather<64, 3, false, false, true><<<gR, TB, 0, stream>>>(B1, nullptr, (float*)d_out,
                                                             rp_ib, ent_ibn, rp_in, ent_in,
                                                             rp_out, ent_out, N);
}

// Round 4
// 1117.602 us; speedup vs baseline: 10.8214x; 1.3279x over previous
//
#include <hip/hip_runtime.h>

// ---------------------------------------------------------------------------
// DiGCN_IB_3MixBN_SymCat — round 4: MFMA bf16 GEMMs + fused gathers.
// N=50000, E=800000 per set (5 sets), dims 128/128/64.
// bf16 storage everywhere intermediate; f32 accumulate (MFMA acc / gather fma).
// ---------------------------------------------------------------------------

static inline int cdiv(int a, int b) { return (a + b - 1) / b; }

struct __align__(8) Ent { int s; float w; };

using bf16x8 = __attribute__((ext_vector_type(8))) short;
using f32x4  = __attribute__((ext_vector_type(4))) float;

__device__ __forceinline__ float b2f(uint u)  { return __uint_as_float(u << 16); }
__device__ __forceinline__ float b2fh(uint u) { return __uint_as_float(u & 0xFFFF0000u); }
__device__ __forceinline__ ushort f2b(float f) {
  uint u = __float_as_uint(f);
  return (ushort)((u + 0x7FFFu + ((u >> 16) & 1u)) >> 16);
}

// ---------------- prep kernels ----------------

__global__ void k_cvt(const float* __restrict__ s, ushort* __restrict__ d, int n) {
  int i = (blockIdx.x * blockDim.x + threadIdx.x) * 4;
  if (i >= n) return;
  float4 v = *reinterpret_cast<const float4*>(s + i);
  ushort4 o;
  o.x = f2b(v.x); o.y = f2b(v.y); o.z = f2b(v.z); o.w = f2b(v.w);
  *reinterpret_cast<ushort4*>(d + i) = o;
}

struct DegJob { const int* src; const int* dst; const float* w; float* deg; int* cnt; int E; };
struct DegJobs { DegJob j[5]; };

__global__ void k_degcnt_all(DegJobs jobs) {
  DegJob jb = jobs.j[blockIdx.y];
  int e = blockIdx.x * blockDim.x + threadIdx.x;
  if (e >= jb.E) return;
  if (jb.deg) unsafeAtomicAdd(&jb.deg[jb.src[e]], jb.w ? jb.w[e] : 1.0f);
  atomicAdd(&jb.cnt[jb.dst[e]], 1);
}

__global__ void k_rsqrt(float* __restrict__ d, int n) {
  int i = blockIdx.x * blockDim.x + threadIdx.x;
  if (i < n) {
    float v = d[i];
    d[i] = (v > 0.0f) ? rsqrtf(v) : 0.0f;
  }
}

// one block per set: exclusive scan cnt[set][0..N) -> rptr[set][0..N]; cnt becomes cursor
__global__ __launch_bounds__(1024) void k_scan(int* __restrict__ cnt,
                                               int* __restrict__ rptr, int N) {
  int* c = cnt + (size_t)blockIdx.x * N;
  int* r = rptr + (size_t)blockIdx.x * (N + 1);
  __shared__ int lds[1024];
  int carry = 0;
  for (int base = 0; base < N; base += 1024) {
    int i = base + threadIdx.x;
    int v = (i < N) ? c[i] : 0;
    lds[threadIdx.x] = v;
    __syncthreads();
#pragma unroll
    for (int d = 1; d < 1024; d <<= 1) {
      int t = (threadIdx.x >= d) ? lds[threadIdx.x - d] : 0;
      __syncthreads();
      lds[threadIdx.x] += t;
      __syncthreads();
    }
    if (i < N) {
      int ex = carry + lds[threadIdx.x] - v;   // exclusive
      r[i] = ex;
      c[i] = ex;                               // cursor init
    }
    carry += lds[1023];
    __syncthreads();
  }
  if (threadIdx.x == 0) r[N] = carry;
}

struct FillJob {
  const int* src; const int* dst; const float* w; const float* dinv;
  int* cur; Ent* entA; Ent* entB; int rawA; int E;
};
struct FillJobs { FillJob j[5]; };

__global__ void k_fill_all(FillJobs jobs) {
  FillJob jb = jobs.j[blockIdx.y];
  int e = blockIdx.x * blockDim.x + threadIdx.x;
  if (e >= jb.E) return;
  int s = jb.src[e], d = jb.dst[e];
  float ww = jb.w ? jb.w[e] : 1.0f;
  float wA = jb.rawA ? ww : jb.dinv[s] * ww * jb.dinv[d];
  int pos = atomicAdd(&jb.cur[d], 1);
  jb.entA[pos].s = s; jb.entA[pos].w = wA;
  if (jb.entB) { jb.entB[pos].s = s; jb.entB[pos].w = jb.dinv[s] * jb.dinv[d]; }
}

struct CvtJob { const float* s; ushort* d; int n; };
struct CvtJobs { CvtJob j[5]; };

__global__ void k_cvtw_all(CvtJobs jobs) {
  CvtJob jb = jobs.j[blockIdx.y];
  int i = (blockIdx.x * blockDim.x + threadIdx.x) * 4;
  if (i >= jb.n) return;
  float4 v = *reinterpret_cast<const float4*>(jb.s + i);
  ushort4 o;
  o.x = f2b(v.x); o.y = f2b(v.y); o.z = f2b(v.z); o.w = f2b(v.w);
  *reinterpret_cast<ushort4*>(jb.d + i) = o;
}

struct TrJob { const float* s; ushort* d; };
struct TrJobs { TrJob j[4]; };

// 128x128 [k][m] -> bf16 [m][k]
__global__ void k_trw_all(TrJobs jobs) {
  TrJob jb = jobs.j[blockIdx.y];
  int i = blockIdx.x * blockDim.x + threadIdx.x;
  if (i >= 128 * 128) return;
  int m = i >> 7, k = i & 127;
  jb.d[i] = f2b(jb.s[k * 128 + m]);
}

__global__ void k_bias3(const float* __restrict__ a, const float* __restrict__ b,
                        const float* __restrict__ c, float* __restrict__ o, int n) {
  int i = blockIdx.x * blockDim.x + threadIdx.x;
  if (i < n) o[i] = a[i] + b[i] + c[i];
}

// ---------------- MFMA GEMM ----------------
// C[n][m] = act( sum_k A[n][k]*W[m][k] + bias[m] )   (W pre-transposed to [m][k] bf16)
// A bf16, split at K1 (A1 stride K1 | A2 stride K-K1). Block: 64 rows x BN cols,
// 4 waves. BN=128: 2x2 waves (tile 32x64); BN=64: 4x1 waves (tile 16x64).
// A/B fragments use identical contiguous-8 k-slot mapping (layout-agnostic);
// C/D mapping col=lane&15, row=(lane>>4)*4+reg (HW-verified).
template <int K, int K1, int BN, bool RELU>
__global__ __launch_bounds__(256) void k_mgemm(
    const ushort* A1, const ushort* A2,
    const ushort* __restrict__ Wt, const float* __restrict__ bias,
    ushort* C, int N) {
  constexpr int WAVES_N = BN / 64;          // 2 or 1
  constexpr int WAVES_M = 4 / WAVES_N;      // 2 or 4
  constexpr int TM = 64 / WAVES_M;          // 32 or 16
  constexpr int MF = TM / 16;               // 2 or 1
  constexpr int NF = 4;                     // 64 cols per wave

  const int tid = threadIdx.x;
  const int wid = tid >> 6;
  const int lane = tid & 63;
  const int lr = lane & 15;
  const int g = lane >> 4;
  const int wm = wid / WAVES_N;
  const int wnn = wid % WAVES_N;
  const int row0 = blockIdx.x * 64 + wm * TM;
  const int col0 = wnn * 64;

  f32x4 acc[MF][NF];
#pragma unroll
  for (int mi = 0; mi < MF; mi++)
#pragma unroll
    for (int ni = 0; ni < NF; ni++)
#pragma unroll
      for (int r = 0; r < 4; r++) acc[mi][ni][r] = 0.0f;

#pragma unroll
  for (int kk = 0; kk < K / 32; kk++) {
    const ushort* A; int lda, kofs;
    if (kk * 32 < K1) { A = A1; lda = K1; kofs = kk * 32; }
    else              { A = A2; lda = K - K1; kofs = kk * 32 - K1; }
    bf16x8 af[MF], bfr[NF];
#pragma unroll
    for (int mi = 0; mi < MF; mi++)
      af[mi] = *reinterpret_cast<const bf16x8*>(
          A + (size_t)(row0 + mi * 16 + lr) * lda + kofs + 8 * g);
#pragma unroll
    for (int ni = 0; ni < NF; ni++)
      bfr[ni] = *reinterpret_cast<const bf16x8*>(
          Wt + (size_t)(col0 + ni * 16 + lr) * K + kk * 32 + 8 * g);
#pragma unroll
    for (int mi = 0; mi < MF; mi++)
#pragma unroll
      for (int ni = 0; ni < NF; ni++)
        acc[mi][ni] = __builtin_amdgcn_mfma_f32_16x16x32_bf16(
            af[mi], bfr[ni], acc[mi][ni], 0, 0, 0);
  }

  __syncthreads();   // allows C to alias A (all A-reads of this block done)

  float bv[NF];
#pragma unroll
  for (int ni = 0; ni < NF; ni++) bv[ni] = bias ? bias[col0 + ni * 16 + lr] : 0.0f;

#pragma unroll
  for (int mi = 0; mi < MF; mi++)
#pragma unroll
    for (int r = 0; r < 4; r++) {
      int row = row0 + mi * 16 + g * 4 + r;
      if (row >= N) continue;
#pragma unroll
      for (int ni = 0; ni < NF; ni++) {
        float v = acc[mi][ni][r] + bv[ni];
        if (RELU) v = fmaxf(v, 0.0f);
        C[(size_t)row * BN + col0 + ni * 16 + lr] = f2b(v);
      }
    }
}

// ---------------- CSR gather ----------------
// out[row] = act( (BASE? base[row]:0) + sum over NS sets of w * X_set[src] )
template <int M, int NS, bool RELU, bool BASE, bool OUTF32>
__global__ __launch_bounds__(256) void k_gather(
    const ushort* __restrict__ base, void* __restrict__ outv,
    const int* __restrict__ rp0, const Ent* __restrict__ e0, const ushort* __restrict__ X0,
    const int* __restrict__ rp1, const Ent* __restrict__ e1, const ushort* __restrict__ X1,
    const int* __restrict__ rp2, const Ent* __restrict__ e2, const ushort* __restrict__ X2,
    int N) {
  int row = blockIdx.x * 4 + (threadIdx.x >> 6);
  if (row >= N) return;
  int lane = threadIdx.x & 63;

  if constexpr (M == 128) {
    float ax = 0.0f, ay = 0.0f;
    if constexpr (BASE) {
      uint b = *reinterpret_cast<const uint*>(base + (size_t)row * 128 + lane * 2);
      ax = b2f(b); ay = b2fh(b);
    }
    auto doSet = [&](const int* __restrict__ rp, const Ent* __restrict__ ee,
                     const ushort* __restrict__ X) {
      int i = rp[row], en = rp[row + 1];
      for (; i + 4 <= en; i += 4) {
        Ent a0 = ee[i], a1 = ee[i + 1], a2 = ee[i + 2], a3 = ee[i + 3];
        uint b0 = *reinterpret_cast<const uint*>(X + (size_t)a0.s * 128 + lane * 2);
        uint b1 = *reinterpret_cast<const uint*>(X + (size_t)a1.s * 128 + lane * 2);
        uint b2 = *reinterpret_cast<const uint*>(X + (size_t)a2.s * 128 + lane * 2);
        uint b3 = *reinterpret_cast<const uint*>(X + (size_t)a3.s * 128 + lane * 2);
        ax = fmaf(a0.w, b2f(b0), ax); ay = fmaf(a0.w, b2fh(b0), ay);
        ax = fmaf(a1.w, b2f(b1), ax); ay = fmaf(a1.w, b2fh(b1), ay);
        ax = fmaf(a2.w, b2f(b2), ax); ay = fmaf(a2.w, b2fh(b2), ay);
        ax = fmaf(a3.w, b2f(b3), ax); ay = fmaf(a3.w, b2fh(b3), ay);
      }
      for (; i < en; ++i) {
        Ent a = ee[i];
        uint b = *reinterpret_cast<const uint*>(X + (size_t)a.s * 128 + lane * 2);
        ax = fmaf(a.w, b2f(b), ax); ay = fmaf(a.w, b2fh(b), ay);
      }
    };
    doSet(rp0, e0, X0);
    if constexpr (NS > 1) doSet(rp1, e1, X1);
    if constexpr (NS > 2) doSet(rp2, e2, X2);
    if constexpr (RELU) { ax = fmaxf(ax, 0.0f); ay = fmaxf(ay, 0.0f); }
    if constexpr (OUTF32) {
      *reinterpret_cast<float2*>((float*)outv + (size_t)row * 128 + lane * 2) =
          make_float2(ax, ay);
    } else {
      uint pk = (uint)f2b(ax) | ((uint)f2b(ay) << 16);
      *reinterpret_cast<uint*>((ushort*)outv + (size_t)row * 128 + lane * 2) = pk;
    }
  } else {  // M == 64
    float acc = 0.0f;
    if constexpr (BASE) acc = b2f((uint)base[(size_t)row * 64 + lane]);
    auto doSet = [&](const int* __restrict__ rp, const Ent* __restrict__ ee,
                     const ushort* __restrict__ X) {
      int i = rp[row], en = rp[row + 1];
      for (; i + 4 <= en; i += 4) {
        Ent a0 = ee[i], a1 = ee[i + 1], a2 = ee[i + 2], a3 = ee[i + 3];
        float v0 = b2f((uint)X[(size_t)a0.s * 64 + lane]);
        float v1 = b2f((uint)X[(size_t)a1.s * 64 + lane]);
        float v2 = b2f((uint)X[(size_t)a2.s * 64 + lane]);
        float v3 = b2f((uint)X[(size_t)a3.s * 64 + lane]);
        acc = fmaf(a0.w, v0, acc); acc = fmaf(a1.w, v1, acc);
        acc = fmaf(a2.w, v2, acc); acc = fmaf(a3.w, v3, acc);
      }
      for (; i < en; ++i) {
        Ent a = ee[i];
        acc = fmaf(a.w, b2f((uint)X[(size_t)a.s * 64 + lane]), acc);
      }
    };
    doSet(rp0, e0, X0);
    if constexpr (NS > 1) doSet(rp1, e1, X1);
    if constexpr (NS > 2) doSet(rp2, e2, X2);
    if constexpr (RELU) acc = fmaxf(acc, 0.0f);
    if constexpr (OUTF32) ((float*)outv)[(size_t)row * 64 + lane] = acc;
    else                  ((ushort*)outv)[(size_t)row * 64 + lane] = f2b(acc);
  }
}

// ---------------- launch ----------------

extern "C" void kernel_launch(void* const* d_in, const int* in_sizes, int n_in,
                              void* d_out, int out_size, void* d_ws, size_t ws_size,
                              hipStream_t stream) {
  const float* x        = (const float*)d_in[0];
  const int*   ei_sym   = (const int*)d_in[1];
  const int*   ei_in    = (const int*)d_in[2];
  const float* in_w     = (const float*)d_in[3];
  const int*   ei_out   = (const int*)d_in[4];
  const float* out_w    = (const float*)d_in[5];
  const int*   ei_ib    = (const int*)d_in[6];
  const float* w_ib     = (const float*)d_in[7];
  const int*   ei_ib2   = (const int*)d_in[8];
  const float* w_ib2    = (const float*)d_in[9];
  const float* lin1_w   = (const float*)d_in[10];
  const float* lin2_w   = (const float*)d_in[11];
  const float* ib1_ln_w = (const float*)d_in[12];
  const float* ib1_ln_b = (const float*)d_in[13];
  const float* ib1_c1_w = (const float*)d_in[14];
  const float* ib1_c1_b = (const float*)d_in[15];
  const float* ib1_c2_w = (const float*)d_in[16];
  const float* ib1_c2_b = (const float*)d_in[17];
  const float* ib2_ln_w = (const float*)d_in[18];
  const float* ib2_ln_b = (const float*)d_in[19];
  const float* ib2_c1_w = (const float*)d_in[20];
  const float* ib2_c1_b = (const float*)d_in[21];
  const float* ib2_c2_w = (const float*)d_in[22];
  const float* ib2_c2_b = (const float*)d_in[23];
  const float* conv1_w  = (const float*)d_in[24];
  const float* conv1_b  = (const float*)d_in[25];

  const int N = in_sizes[0] / 128;
  const int E = in_sizes[1] / 2;

  size_t off = 0;
  auto alloc = [&](size_t bytes) -> void* {
    void* p = (char*)d_ws + off;
    off = (off + bytes + 255) & ~size_t(255);
    return p;
  };
  ushort* xb = (ushort*)alloc((size_t)N * 128 * 2);   // x bf16; later reused as B4
  ushort* B0 = (ushort*)alloc((size_t)N * 128 * 2);
  ushort* B1 = (ushort*)alloc((size_t)N * 128 * 2);
  ushort* B2 = (ushort*)alloc((size_t)N * 128 * 2);
  ushort* B3 = (ushort*)alloc((size_t)N * 128 * 2);
  ushort* B4 = xb;                                    // alias (xb dead after stage-1 GEMMs)
  Ent* ent_sym = (Ent*)alloc((size_t)E * 8);
  Ent* ent_in  = (Ent*)alloc((size_t)E * 8);
  Ent* ent_out = (Ent*)alloc((size_t)E * 8);
  Ent* ent_ibr = (Ent*)alloc((size_t)E * 8);
  Ent* ent_ibn = (Ent*)alloc((size_t)E * 8);
  Ent* ent_ib2 = (Ent*)alloc((size_t)E * 8);
  int* rptr = (int*)alloc(5 * (size_t)(N + 1) * 4);
  int* cnt  = (int*)alloc(5 * (size_t)N * 4);
  float* deg = (float*)alloc(4 * (size_t)N * 4);
  ushort* Wb_lin1  = (ushort*)alloc(128 * 128 * 2);
  ushort* Wb_ib1ln = (ushort*)alloc(128 * 128 * 2);
  ushort* Wb_ib2ln = (ushort*)alloc(128 * 128 * 2);
  ushort* Wb_conv1 = (ushort*)alloc(128 * 256 * 2);
  ushort* Wb_lin2  = (ushort*)alloc(64 * 128 * 2);
  ushort* Wb_ib1c1 = (ushort*)alloc(128 * 128 * 2);
  ushort* Wb_ib1c2 = (ushort*)alloc(128 * 128 * 2);
  ushort* Wb_ib2c1 = (ushort*)alloc(128 * 128 * 2);
  ushort* Wb_ib2c2 = (ushort*)alloc(128 * 128 * 2);
  float* bias1 = (float*)alloc(128 * 4);
  float* bias2 = (float*)alloc(128 * 4);

  const int TB = 256;
  const int gE = cdiv(E, TB);
  const int gM = cdiv(N, 64);   // mfma gemm grid
  const int gR = cdiv(N, 4);    // gather grid

  const int* rp_sym = rptr + 0 * (N + 1);
  const int* rp_in  = rptr + 1 * (N + 1);
  const int* rp_out = rptr + 2 * (N + 1);
  const int* rp_ib  = rptr + 3 * (N + 1);
  const int* rp_ib2 = rptr + 4 * (N + 1);

  // ---- 1. x->bf16, degrees+counts ----
  k_cvt<<<cdiv(N * 128, TB * 4), TB, 0, stream>>>(x, xb, N * 128);
  hipMemsetAsync(deg, 0, 4 * (size_t)N * sizeof(float), stream);
  hipMemsetAsync(cnt, 0, 5 * (size_t)N * sizeof(int), stream);
  {
    DegJobs dj;
    dj.j[0] = { ei_sym, ei_sym + E, nullptr, deg + 0 * N, cnt + 0 * N, E };
    dj.j[1] = { ei_in,  ei_in + E,  in_w,    deg + 1 * N, cnt + 1 * N, E };
    dj.j[2] = { ei_out, ei_out + E, out_w,   deg + 2 * N, cnt + 2 * N, E };
    dj.j[3] = { ei_ib,  ei_ib + E,  nullptr, deg + 3 * N, cnt + 3 * N, E };
    dj.j[4] = { ei_ib2, ei_ib2 + E, nullptr, nullptr,     cnt + 4 * N, E };
    dim3 g(gE, 5);
    k_degcnt_all<<<g, TB, 0, stream>>>(dj);
  }
  k_rsqrt<<<cdiv(4 * N, TB), TB, 0, stream>>>(deg, 4 * N);

  // ---- 2. CSR build ----
  k_scan<<<5, 1024, 0, stream>>>(cnt, rptr, N);
  {
    FillJobs fj;
    fj.j[0] = { ei_sym, ei_sym + E, nullptr, deg + 0 * N, cnt + 0 * N, ent_sym, nullptr, 0, E };
    fj.j[1] = { ei_in,  ei_in + E,  in_w,    deg + 1 * N, cnt + 1 * N, ent_in,  nullptr, 0, E };
    fj.j[2] = { ei_out, ei_out + E, out_w,   deg + 2 * N, cnt + 2 * N, ent_out, nullptr, 0, E };
    fj.j[3] = { ei_ib,  ei_ib + E,  w_ib,    deg + 3 * N, cnt + 3 * N, ent_ibr, ent_ibn, 1, E };
    fj.j[4] = { ei_ib2, ei_ib2 + E, w_ib2,   nullptr,     cnt + 4 * N, ent_ib2, nullptr, 1, E };
    dim3 g(gE, 5);
    k_fill_all<<<g, TB, 0, stream>>>(fj);
  }

  // ---- 3. weight prep ----
  {
    CvtJobs cj;
    cj.j[0] = { lin1_w,   Wb_lin1,  128 * 128 };
    cj.j[1] = { ib1_ln_w, Wb_ib1ln, 128 * 128 };
    cj.j[2] = { ib2_ln_w, Wb_ib2ln, 128 * 128 };
    cj.j[3] = { conv1_w,  Wb_conv1, 128 * 256 };
    cj.j[4] = { lin2_w,   Wb_lin2,  64 * 128 };
    dim3 g(cdiv(128 * 256, TB * 4), 5);
    k_cvtw_all<<<g, TB, 0, stream>>>(cj);
  }
  {
    TrJobs tj;
    tj.j[0] = { ib1_c1_w, Wb_ib1c1 };
    tj.j[1] = { ib1_c2_w, Wb_ib1c2 };
    tj.j[2] = { ib2_c1_w, Wb_ib2c1 };
    tj.j[3] = { ib2_c2_w, Wb_ib2c2 };
    dim3 g(cdiv(128 * 128, TB), 4);
    k_trw_all<<<g, TB, 0, stream>>>(tj);
  }
  k_bias3<<<1, 128, 0, stream>>>(ib1_ln_b, ib1_c1_b, ib1_c2_b, bias1, 128);
  k_bias3<<<1, 128, 0, stream>>>(ib2_ln_b, ib2_c1_b, ib2_c2_b, bias2, 128);

  // ---- 4. stage 1 ----
  k_mgemm<128, 128, 128, false><<<gM, TB, 0, stream>>>(xb, nullptr, Wb_lin1,  nullptr, B0, N); // symx
  k_mgemm<128, 128, 128, false><<<gM, TB, 0, stream>>>(xb, nullptr, Wb_ib1ln, bias1,   B2, N); // hbase
  k_mgemm<128, 128, 128, false><<<gM, TB, 0, stream>>>(xb, nullptr, Wb_ib1c1, nullptr, B3, N); // xw1
  k_mgemm<128, 128, 128, false><<<gM, TB, 0, stream>>>(xb, nullptr, Wb_ib1c2, nullptr, B4, N); // xw2 (in-place alias)
  // B2 += ib(xw1) + ib2(xw2)
  k_gather<128, 2, false, true, false><<<gR, TB, 0, stream>>>(
      B2, B2, rp_ib, ent_ibr, B3, rp_ib2, ent_ib2, B4, nullptr, nullptr, nullptr, N);
  // symagg = sym+in+out over symx
  k_gather<128, 3, false, false, false><<<gR, TB, 0, stream>>>(
      nullptr, B1, rp_sym, ent_sym, B0, rp_in, ent_in, B0, rp_out, ent_out, B0, N);
  // h = relu(concat(B2,B1) @ conv1^T + b) -> B0
  k_mgemm<256, 128, 128, true><<<gM, TB, 0, stream>>>(B2, B1, Wb_conv1, conv1_b, B0, N);

  // ---- 5. stage 2 (h = B0) ----
  k_mgemm<128, 128, 128, false><<<gM, TB, 0, stream>>>(B0, nullptr, Wb_ib2ln, bias2,   B2, N);
  k_mgemm<128, 128, 128, false><<<gM, TB, 0, stream>>>(B0, nullptr, Wb_ib2c1, nullptr, B3, N);
  k_mgemm<128, 128, 128, false><<<gM, TB, 0, stream>>>(B0, nullptr, Wb_ib2c2, nullptr, B4, N);
  // B2 = relu(B2 + ib(B3) + ib2(B4))
  k_gather<128, 2, true, true, false><<<gR, TB, 0, stream>>>(
      B2, B2, rp_ib, ent_ibr, B3, rp_ib2, ent_ib2, B4, nullptr, nullptr, nullptr, N);

  // ---- 6. symx2 = B2 @ lin2^T -> B1 (64-dim) ----
  k_mgemm<128, 128, 64, false><<<gM, TB, 0, stream>>>(B2, nullptr, Wb_lin2, nullptr, B1, N);

  // ---- 7. out (f32) = ib_norm + in + out gathers over B1 ----
  k_gather<64, 3, false, false, true><<<gR, TB, 0, stream>>>(
      nullptr, (float*)d_out, rp_ib, ent_ibn, B1, rp_in, ent_in, B1, rp_out, ent_out, B1, N);
}